// Round 1
// baseline (375.108 us; speedup 1.0000x reference)
//
#include <hip/hip_runtime.h>

typedef float  f32x4  __attribute__((ext_vector_type(4)));
typedef __bf16 bf16x8 __attribute__((ext_vector_type(8)));
typedef __bf16 bf16x4 __attribute__((ext_vector_type(4)));

#define H2S 136   // padded LDS leading dim (bf16 elems): 128 + 8

__device__ __forceinline__ float fast_tanh(float x) {
    // tanh(x) = 1 - 2/(exp(2x)+1); safe at +/-inf (e=inf -> 1, e=0 -> -1)
    float e = __expf(2.0f * x);
    return 1.0f - 2.0f / (e + 1.0f);
}

__global__ __launch_bounds__(256, 4) void commnet_kernel(
    const float* __restrict__ obs,
    const float* __restrict__ wH1,
    const float* __restrict__ wH2,
    const float* __restrict__ wC2,
    const float* __restrict__ wOut,
    const float* __restrict__ bOut,
    float* __restrict__ out)
{
    __shared__ __align__(16) float  psum[256 * 4];
    __shared__ __align__(16) float  sumH1[128];
    __shared__ __align__(16) __bf16 h2s[64 * H2S];
    __shared__ __align__(16) __bf16 wbs[16 * H2S];

    const int t  = threadIdx.x;
    const int b  = blockIdx.x;
    const int dg = t & 31;   // d-group: d0 = dg*4
    const int ng = t >> 5;   // n-offset: n = ng + 8k
    const int d0 = dg * 4;

    // --- stage w_out (128x16 f32) -> wbs[o][d] transposed bf16 (B-frag layout)
    {
        const f32x4* w4 = (const f32x4*)wOut;
        #pragma unroll
        for (int i = 0; i < 2; ++i) {
            int idx4 = t + 256 * i;      // 512 float4 total
            f32x4 v  = w4[idx4];
            int e = idx4 * 4;
            int d = e >> 4;
            int o = e & 15;              // multiple of 4
            #pragma unroll
            for (int j = 0; j < 4; ++j)
                wbs[(o + j) * H2S + d] = (__bf16)v[j];
        }
    }

    const f32x4 wh1v = *(const f32x4*)(wH1 + d0);
    const f32x4 wh2v = *(const f32x4*)(wH2 + d0);
    const f32x4 wc2v = *(const f32x4*)(wC2 + d0);

    // --- phase 1: load obs (coalesced float4), H1 = tanh(wH1*obs), partial sums
    const f32x4* obs4 = (const f32x4*)obs + (size_t)b * 2048;
    f32x4 obs_r[8], h1_r[8];
    f32x4 ps = {0.f, 0.f, 0.f, 0.f};
    #pragma unroll
    for (int k = 0; k < 8; ++k) {
        f32x4 o4 = obs4[t + 256 * k];
        obs_r[k] = o4;
        f32x4 h;
        #pragma unroll
        for (int j = 0; j < 4; ++j) h[j] = fast_tanh(wh1v[j] * o4[j]);
        h1_r[k] = h;
        ps += h;
    }
    *(f32x4*)&psum[t * 4] = ps;
    __syncthreads();

    // --- phase 2: reduce 8 n-groups -> sumH1[d]
    if (t < 128) {
        int dgr = t >> 2, jr = t & 3;
        float s = 0.f;
        #pragma unroll
        for (int g = 0; g < 8; ++g) s += psum[(g * 32 + dgr) * 4 + jr];
        sumH1[t] = s;
    }
    __syncthreads();

    // --- phase 3: H2 = tanh(wH2*H1 + wC2*C1) + obs -> bf16 LDS tile
    const f32x4 s4 = *(const f32x4*)&sumH1[d0];
    const float inv63 = 1.0f / 63.0f;
    #pragma unroll
    for (int k = 0; k < 8; ++k) {
        int n = ng + 8 * k;
        f32x4 h1  = h1_r[k];
        f32x4 c1  = (s4 - h1) * inv63;
        f32x4 pre = wh2v * h1 + wc2v * c1;
        bf16x4 hb;
        #pragma unroll
        for (int j = 0; j < 4; ++j)
            hb[j] = (__bf16)(fast_tanh(pre[j]) + obs_r[k][j]);
        *(bf16x4*)&h2s[n * H2S + d0] = hb;
    }
    __syncthreads();

    // --- phase 4: H2[64x128] @ wOut[128x16] via mfma_f32_16x16x32_bf16
    // wave w handles rows 16w..16w+15; K=128 in 4 steps of 32.
    const int w    = t >> 6;
    const int l    = t & 63;
    const int m16  = l & 15;
    const int quad = l >> 4;
    f32x4 acc = {0.f, 0.f, 0.f, 0.f};
    const __bf16* aP = &h2s[(w * 16 + m16) * H2S + quad * 8];
    const __bf16* bP = &wbs[m16 * H2S + quad * 8];
    #pragma unroll
    for (int ks = 0; ks < 4; ++ks) {
        bf16x8 a  = *(const bf16x8*)(aP + ks * 32);
        bf16x8 bb = *(const bf16x8*)(bP + ks * 32);
        acc = __builtin_amdgcn_mfma_f32_16x16x32_bf16(a, bb, acc, 0, 0, 0);
    }
    // C/D layout: col = lane&15, row = (lane>>4)*4 + reg   [m89-verified]
    const float bo = bOut[m16];
    float* op = out + (size_t)b * 1024 + m16;
    #pragma unroll
    for (int r = 0; r < 4; ++r) {
        int row = w * 16 + quad * 4 + r;
        op[row * 16] = acc[r] + bo;
    }
}

extern "C" void kernel_launch(void* const* d_in, const int* in_sizes, int n_in,
                              void* d_out, int out_size, void* d_ws, size_t ws_size,
                              hipStream_t stream) {
    const float* obs  = (const float*)d_in[0];
    const float* wH1  = (const float*)d_in[1];
    // d_in[2] = w_C1: unused (C0 = 0 so w_C1*C0 contributes nothing)
    const float* wH2  = (const float*)d_in[3];
    const float* wC2  = (const float*)d_in[4];
    const float* wOut = (const float*)d_in[5];
    const float* bOut = (const float*)d_in[6];
    float* out = (float*)d_out;

    commnet_kernel<<<8192, 256, 0, stream>>>(obs, wH1, wH2, wC2, wOut, bOut, out);
}

// Round 2
// 374.577 us; speedup vs baseline: 1.0014x; 1.0014x over previous
//
#include <hip/hip_runtime.h>

typedef float  f32x4  __attribute__((ext_vector_type(4)));
typedef __bf16 bf16x8 __attribute__((ext_vector_type(8)));
typedef __bf16 bf16x4 __attribute__((ext_vector_type(4)));

#define H2S 136   // padded LDS leading dim (bf16 elems): 128 + 8

__device__ __forceinline__ float fast_tanh(float x) {
    // tanh(x) = 1 - 2/(exp(2x)+1); v_exp_f32 + v_rcp_f32, NO IEEE div sequence.
    // Safe at +/-inf: e=inf -> rcp=0 -> 1; e=0 -> rcp(1)=1 -> -1.
    float e = __expf(2.0f * x);
    float r = __builtin_amdgcn_rcpf(e + 1.0f);
    return __builtin_fmaf(-2.0f, r, 1.0f);   // 1 - 2r, inline consts
}

__global__ __launch_bounds__(256, 4) void commnet_kernel(
    const float* __restrict__ obs,
    const float* __restrict__ wH1,
    const float* __restrict__ wH2,
    const float* __restrict__ wC2,
    const float* __restrict__ wOut,
    const float* __restrict__ bOut,
    float* __restrict__ out)
{
    __shared__ __align__(16) float  psum[256 * 4];
    __shared__ __align__(16) float  sumH1[128];
    __shared__ __align__(16) __bf16 h2s[64 * H2S];
    __shared__ __align__(16) __bf16 wbs[16 * H2S];

    const int t  = threadIdx.x;
    const int b  = blockIdx.x;
    const int dg = t & 31;   // d-group: d0 = dg*4
    const int ng = t >> 5;   // n-offset: n = ng + 8k
    const int d0 = dg * 4;

    // --- issue obs loads FIRST (8x global_load_dwordx4, coalesced)
    const f32x4* obs4 = (const f32x4*)obs + (size_t)b * 2048;
    f32x4 obs_r[8];
    #pragma unroll
    for (int k = 0; k < 8; ++k) obs_r[k] = obs4[t + 256 * k];

    // --- stage w_out (128x16 f32) -> wbs[o][d] transposed bf16 (B-frag layout)
    {
        const f32x4* w4 = (const f32x4*)wOut;
        #pragma unroll
        for (int i = 0; i < 2; ++i) {
            int idx4 = t + 256 * i;      // 512 float4 total
            f32x4 v  = w4[idx4];
            int e = idx4 * 4;
            int d = e >> 4;
            int o = e & 15;              // multiple of 4
            #pragma unroll
            for (int j = 0; j < 4; ++j)
                wbs[(o + j) * H2S + d] = (__bf16)v[j];
        }
    }

    const f32x4 wh1v = *(const f32x4*)(wH1 + d0);
    const f32x4 wh2v = *(const f32x4*)(wH2 + d0);
    const f32x4 wc2v = *(const f32x4*)(wC2 + d0);

    // --- phase 1: H1 = tanh(wH1*obs), partial sums over this thread's 8 rows
    f32x4 h1_r[8];
    f32x4 ps = {0.f, 0.f, 0.f, 0.f};
    #pragma unroll
    for (int k = 0; k < 8; ++k) {
        f32x4 o4 = obs_r[k];
        f32x4 h;
        #pragma unroll
        for (int j = 0; j < 4; ++j) h[j] = fast_tanh(wh1v[j] * o4[j]);
        h1_r[k] = h;
        ps += h;
    }
    *(f32x4*)&psum[t * 4] = ps;
    __syncthreads();

    // --- phase 2: reduce 8 n-groups -> sumH1[d]
    if (t < 128) {
        int dgr = t >> 2, jr = t & 3;
        float s = 0.f;
        #pragma unroll
        for (int g = 0; g < 8; ++g) s += psum[(g * 32 + dgr) * 4 + jr];
        sumH1[t] = s;
    }
    __syncthreads();

    // --- phase 3: H2 = tanh(wH2*H1 + wC2*C1) + obs -> bf16 LDS tile
    const f32x4 s4 = *(const f32x4*)&sumH1[d0];
    const float inv63 = 1.0f / 63.0f;
    #pragma unroll
    for (int k = 0; k < 8; ++k) {
        int n = ng + 8 * k;
        f32x4 h1  = h1_r[k];
        f32x4 c1  = (s4 - h1) * inv63;
        f32x4 pre = wh2v * h1 + wc2v * c1;
        bf16x4 hb;
        #pragma unroll
        for (int j = 0; j < 4; ++j)
            hb[j] = (__bf16)(fast_tanh(pre[j]) + obs_r[k][j]);
        *(bf16x4*)&h2s[n * H2S + d0] = hb;
    }
    __syncthreads();

    // --- phase 4: H2[64x128] @ wOut[128x16] via mfma_f32_16x16x32_bf16
    // wave w handles rows 16w..16w+15; K=128 in 4 steps of 32.
    const int w    = t >> 6;
    const int l    = t & 63;
    const int m16  = l & 15;
    const int quad = l >> 4;
    f32x4 acc = {0.f, 0.f, 0.f, 0.f};
    const __bf16* aP = &h2s[(w * 16 + m16) * H2S + quad * 8];
    const __bf16* bP = &wbs[m16 * H2S + quad * 8];
    #pragma unroll
    for (int ks = 0; ks < 4; ++ks) {
        bf16x8 a  = *(const bf16x8*)(aP + ks * 32);
        bf16x8 bb = *(const bf16x8*)(bP + ks * 32);
        acc = __builtin_amdgcn_mfma_f32_16x16x32_bf16(a, bb, acc, 0, 0, 0);
    }
    // C/D layout: col = lane&15, row = (lane>>4)*4 + reg   [m89-verified]
    const float bo = bOut[m16];
    float* op = out + (size_t)b * 1024 + m16;
    #pragma unroll
    for (int r = 0; r < 4; ++r) {
        int row = w * 16 + quad * 4 + r;
        op[row * 16] = acc[r] + bo;
    }
}

extern "C" void kernel_launch(void* const* d_in, const int* in_sizes, int n_in,
                              void* d_out, int out_size, void* d_ws, size_t ws_size,
                              hipStream_t stream) {
    const float* obs  = (const float*)d_in[0];
    const float* wH1  = (const float*)d_in[1];
    // d_in[2] = w_C1: unused (C0 = 0 so w_C1*C0 contributes nothing)
    const float* wH2  = (const float*)d_in[3];
    const float* wC2  = (const float*)d_in[4];
    const float* wOut = (const float*)d_in[5];
    const float* bOut = (const float*)d_in[6];
    float* out = (float*)d_out;

    commnet_kernel<<<8192, 256, 0, stream>>>(obs, wH1, wH2, wC2, wOut, bOut, out);
}

// Round 4
// 372.765 us; speedup vs baseline: 1.0063x; 1.0049x over previous
//
#include <hip/hip_runtime.h>

typedef float  f32x4  __attribute__((ext_vector_type(4)));
typedef __bf16 bf16x8 __attribute__((ext_vector_type(8)));
typedef __bf16 bf16x4 __attribute__((ext_vector_type(4)));

#define H2S 136   // padded LDS leading dim (bf16 elems): 128 + 8

// Measured (R3 double-launch probe): kernel marginal cost = 49.4 us for
// 302 MB compulsory HBM traffic = 6.11 TB/s = 97% of achievable (6.3 TB/s).
// Remaining ~325 us of bench dur_us is harness reset (1 GiB ws poison +
// input restore) inside the timed region — not addressable from here.

__device__ __forceinline__ float fast_tanh(float x) {
    // tanh(x) = 1 - 2/(exp(2x)+1); v_exp_f32 + v_rcp_f32, NO IEEE div sequence.
    // Safe at +/-inf: e=inf -> rcp=0 -> 1; e=0 -> rcp(1)=1 -> -1.
    float e = __expf(2.0f * x);
    float r = __builtin_amdgcn_rcpf(e + 1.0f);
    return __builtin_fmaf(-2.0f, r, 1.0f);   // 1 - 2r, inline consts
}

__global__ __launch_bounds__(256, 4) void commnet_kernel(
    const float* __restrict__ obs,
    const float* __restrict__ wH1,
    const float* __restrict__ wH2,
    const float* __restrict__ wC2,
    const float* __restrict__ wOut,
    const float* __restrict__ bOut,
    float* __restrict__ out)
{
    __shared__ __align__(16) float  psum[256 * 4];
    __shared__ __align__(16) float  sumH1[128];
    __shared__ __align__(16) __bf16 h2s[64 * H2S];
    __shared__ __align__(16) __bf16 wbs[16 * H2S];

    const int t  = threadIdx.x;
    const int b  = blockIdx.x;
    const int dg = t & 31;   // d-group: d0 = dg*4
    const int ng = t >> 5;   // n-offset: n = ng + 8k
    const int d0 = dg * 4;

    // --- issue obs loads FIRST (8x global_load_dwordx4, coalesced)
    const f32x4* obs4 = (const f32x4*)obs + (size_t)b * 2048;
    f32x4 obs_r[8];
    #pragma unroll
    for (int k = 0; k < 8; ++k) obs_r[k] = obs4[t + 256 * k];

    // --- stage w_out (128x16 f32) -> wbs[o][d] transposed bf16 (B-frag layout)
    {
        const f32x4* w4 = (const f32x4*)wOut;
        #pragma unroll
        for (int i = 0; i < 2; ++i) {
            int idx4 = t + 256 * i;      // 512 float4 total
            f32x4 v  = w4[idx4];
            int e = idx4 * 4;
            int d = e >> 4;
            int o = e & 15;              // multiple of 4
            #pragma unroll
            for (int j = 0; j < 4; ++j)
                wbs[(o + j) * H2S + d] = (__bf16)v[j];
        }
    }

    const f32x4 wh1v = *(const f32x4*)(wH1 + d0);
    const f32x4 wh2v = *(const f32x4*)(wH2 + d0);
    const f32x4 wc2v = *(const f32x4*)(wC2 + d0);

    // --- phase 1: H1 = tanh(wH1*obs), partial sums over this thread's 8 rows
    f32x4 h1_r[8];
    f32x4 ps = {0.f, 0.f, 0.f, 0.f};
    #pragma unroll
    for (int k = 0; k < 8; ++k) {
        f32x4 o4 = obs_r[k];
        f32x4 h;
        #pragma unroll
        for (int j = 0; j < 4; ++j) h[j] = fast_tanh(wh1v[j] * o4[j]);
        h1_r[k] = h;
        ps += h;
    }
    *(f32x4*)&psum[t * 4] = ps;
    __syncthreads();

    // --- phase 2: reduce 8 n-groups -> sumH1[d]
    if (t < 128) {
        int dgr = t >> 2, jr = t & 3;
        float s = 0.f;
        #pragma unroll
        for (int g = 0; g < 8; ++g) s += psum[(g * 32 + dgr) * 4 + jr];
        sumH1[t] = s;
    }
    __syncthreads();

    // --- phase 3: H2 = tanh(wH2*H1 + wC2*C1) + obs -> bf16 LDS tile
    const f32x4 s4 = *(const f32x4*)&sumH1[d0];
    const float inv63 = 1.0f / 63.0f;
    #pragma unroll
    for (int k = 0; k < 8; ++k) {
        int n = ng + 8 * k;
        f32x4 h1  = h1_r[k];
        f32x4 c1  = (s4 - h1) * inv63;
        f32x4 pre = wh2v * h1 + wc2v * c1;
        bf16x4 hb;
        #pragma unroll
        for (int j = 0; j < 4; ++j)
            hb[j] = (__bf16)(fast_tanh(pre[j]) + obs_r[k][j]);
        *(bf16x4*)&h2s[n * H2S + d0] = hb;
    }
    __syncthreads();

    // --- phase 4: H2[64x128] @ wOut[128x16] via mfma_f32_16x16x32_bf16
    // wave w handles rows 16w..16w+15; K=128 in 4 steps of 32.
    const int w    = t >> 6;
    const int l    = t & 63;
    const int m16  = l & 15;
    const int quad = l >> 4;
    f32x4 acc = {0.f, 0.f, 0.f, 0.f};
    const __bf16* aP = &h2s[(w * 16 + m16) * H2S + quad * 8];
    const __bf16* bP = &wbs[m16 * H2S + quad * 8];
    #pragma unroll
    for (int ks = 0; ks < 4; ++ks) {
        bf16x8 a  = *(const bf16x8*)(aP + ks * 32);
        bf16x8 bb = *(const bf16x8*)(bP + ks * 32);
        acc = __builtin_amdgcn_mfma_f32_16x16x32_bf16(a, bb, acc, 0, 0, 0);
    }
    // C/D layout: col = lane&15, row = (lane>>4)*4 + reg   [m89-verified]
    const float bo = bOut[m16];
    float* op = out + (size_t)b * 1024 + m16;
    #pragma unroll
    for (int r = 0; r < 4; ++r) {
        int row = w * 16 + quad * 4 + r;
        op[row * 16] = acc[r] + bo;
    }
}

extern "C" void kernel_launch(void* const* d_in, const int* in_sizes, int n_in,
                              void* d_out, int out_size, void* d_ws, size_t ws_size,
                              hipStream_t stream) {
    const float* obs  = (const float*)d_in[0];
    const float* wH1  = (const float*)d_in[1];
    // d_in[2] = w_C1: unused (C0 = 0 so w_C1*C0 contributes nothing)
    const float* wH2  = (const float*)d_in[3];
    const float* wC2  = (const float*)d_in[4];
    const float* wOut = (const float*)d_in[5];
    const float* bOut = (const float*)d_in[6];
    float* out = (float*)d_out;

    commnet_kernel<<<8192, 256, 0, stream>>>(obs, wH1, wH2, wC2, wOut, bOut, out);
}